// Round 1
// baseline (278.011 us; speedup 1.0000x reference)
//
#include <hip/hip_runtime.h>
#include <cstdint>

#if __has_builtin(__builtin_amdgcn_exp2f)
#define EXP2F(x) __builtin_amdgcn_exp2f(x)
#else
#define EXP2F(x) exp2f(x)
#endif

// Layout facts (from reference):
//  x: (4, 1024, 64, 512) f32; u = x[...,0:256], v = x[...,256:512]
//  d-channel splits as d = vd*16 + s  (s = head = d%16, vd = d/16)
//  head s of block w uses attention params index hb = s*1024 + w
//  score(m,n) = ax*dx + ay*dy - 0.5*(dx^2+dy^2), dx = (n&7)-(m&7), dy = (m>>3)-(n>>3)
//  mixed[m, vd, s] = softmax_n(score) . Us[n, vd, s];  out = (mixed + bias[w,m]) * v

__device__ __forceinline__ void process_head(const float* __restrict__ UsS,
                                             float axl, float ayl,
                                             float mxf, float myf, float biasm,
                                             float* __restrict__ acc)
{
#pragma unroll
    for (int v = 0; v < 16; ++v) acc[v] = 0.0f;
    float sum = 0.0f;
#pragma unroll
    for (int n = 0; n < 64; ++n) {
        const float nx = (float)(n & 7);   // compile-time literal after unroll
        const float ny = (float)(n >> 3);
        const float dx = nx - mxf;
        const float dy = myf - ny;
        // score already scaled by log2(e) via axl/ayl and 0.5*log2e coefficient
        float sc = axl * dx + ayl * dy - 0.72134752f * (dx * dx + dy * dy);
        const float e = EXP2F(sc);
        sum += e;
        const float4 u0 = *(const float4*)(UsS + n * 16 + 0);
        const float4 u1 = *(const float4*)(UsS + n * 16 + 4);
        const float4 u2 = *(const float4*)(UsS + n * 16 + 8);
        const float4 u3 = *(const float4*)(UsS + n * 16 + 12);
        acc[0]  = fmaf(e, u0.x, acc[0]);   acc[1]  = fmaf(e, u0.y, acc[1]);
        acc[2]  = fmaf(e, u0.z, acc[2]);   acc[3]  = fmaf(e, u0.w, acc[3]);
        acc[4]  = fmaf(e, u1.x, acc[4]);   acc[5]  = fmaf(e, u1.y, acc[5]);
        acc[6]  = fmaf(e, u1.z, acc[6]);   acc[7]  = fmaf(e, u1.w, acc[7]);
        acc[8]  = fmaf(e, u2.x, acc[8]);   acc[9]  = fmaf(e, u2.y, acc[9]);
        acc[10] = fmaf(e, u2.z, acc[10]);  acc[11] = fmaf(e, u2.w, acc[11]);
        acc[12] = fmaf(e, u3.x, acc[12]);  acc[13] = fmaf(e, u3.y, acc[13]);
        acc[14] = fmaf(e, u3.z, acc[14]);  acc[15] = fmaf(e, u3.w, acc[15]);
    }
    const float inv = 1.0f / sum;   // softmax denominator folded in after (linearity)
#pragma unroll
    for (int v = 0; v < 16; ++v) acc[v] = acc[v] * inv + biasm;
}

__global__ __launch_bounds__(512, 4) void sgating_kernel(
    const float* __restrict__ x,
    const float* __restrict__ norm_w,
    const float* __restrict__ norm_b,
    const float* __restrict__ centers,
    const float* __restrict__ spreads,
    const float* __restrict__ tbias,
    float* __restrict__ out)
{
    // 64KB LDS: phase 1-2 as Us[s=16][n=64][vd=16] f32; phase 3 reused as
    // mixed[m=64][256] with XOR swizzle col^((m&7)<<2) (16B-align preserved).
    __shared__ float smem[16 * 64 * 16];

    const int t    = threadIdx.x;
    const int wv   = t >> 6;     // wave 0..7
    const int lane = t & 63;
    const int bw   = blockIdx.x;         // b*1024 + w
    const int w_idx = bw & 1023;
    const size_t xbase = (size_t)bw * (64 * 512);

    // ---------------- Phase 1: LayerNorm(u) -> Us ----------------
    {
        const float4 w4 = *(const float4*)(norm_w + lane * 4);
        const float4 b4 = *(const float4*)(norm_b + lane * 4);
#pragma unroll
        for (int r = 0; r < 8; ++r) {
            const int n = wv * 8 + r;
            const float4 u = *(const float4*)(x + xbase + (size_t)n * 512 + lane * 4);
            float s  = u.x + u.y + u.z + u.w;
            float sq = u.x * u.x + u.y * u.y + u.z * u.z + u.w * u.w;
#pragma unroll
            for (int off = 1; off < 64; off <<= 1) {
                s  += __shfl_xor(s, off);
                sq += __shfl_xor(sq, off);
            }
            const float mean = s * (1.0f / 256.0f);
            const float var  = sq * (1.0f / 256.0f) - mean * mean;
            const float rstd = rsqrtf(var + 1e-5f);
            float g[4];
            g[0] = (u.x - mean) * rstd * w4.x + b4.x;
            g[1] = (u.y - mean) * rstd * w4.y + b4.y;
            g[2] = (u.z - mean) * rstd * w4.z + b4.z;
            g[3] = (u.w - mean) * rstd * w4.w + b4.w;
#pragma unroll
            for (int j = 0; j < 4; ++j) {
                const int d = lane * 4 + j;
                // Us[(d&15)][n][d>>4]
                smem[((d & 15) << 10) + (n << 4) + (d >> 4)] = g[j];
            }
        }
    }
    __syncthreads();

    // ---------------- Phase 2: per-head softmax mixing ----------------
    float accA[16], accB[16];
    {
        const float biasm = tbias[w_idx * 64 + lane];
        const float mxf = (float)(lane & 7);
        const float myf = (float)(lane >> 3);
        const float LOG2E = 1.4426950408889634f;
        {
            const int sA = wv;
            const int hb = (sA << 10) | w_idx;
            float a = spreads[hb]; a *= a;
            const float axl = a * centers[2 * hb + 0] * LOG2E;
            const float ayl = a * centers[2 * hb + 1] * LOG2E;
            process_head(smem + (sA << 10), axl, ayl, mxf, myf, biasm, accA);
        }
        {
            const int sB = wv + 8;
            const int hb = (sB << 10) | w_idx;
            float a = spreads[hb]; a *= a;
            const float axl = a * centers[2 * hb + 0] * LOG2E;
            const float ayl = a * centers[2 * hb + 1] * LOG2E;
            process_head(smem + (sB << 10), axl, ayl, mxf, myf, biasm, accB);
        }
    }
    __syncthreads();   // everyone done reading Us; smem becomes mixed[64][256]

    // write mixed: lane = m, heads (wv, wv+8); swizzled column
#pragma unroll
    for (int v = 0; v < 16; ++v) {
        const int cA = (v * 16 + wv)     ^ ((lane & 7) << 2);
        const int cB = (v * 16 + wv + 8) ^ ((lane & 7) << 2);
        smem[(lane << 8) + cA] = accA[v];
        smem[(lane << 8) + cB] = accB[v];
    }
    __syncthreads();

    // ---------------- Phase 3: out = mixed * v (coalesced) ----------------
    const size_t obase = (size_t)bw * (64 * 256);
#pragma unroll
    for (int k = 0; k < 8; ++k) {
        const int flat = (t << 2) + (k << 11);
        const int m = flat >> 8;
        const int c = flat & 255;
        const int cs = c ^ ((m & 7) << 2);   // unswizzle (XOR on bits 2-4 keeps float4 align)
        const float4 mx = *(const float4*)&smem[(m << 8) + cs];
        const float4 vv = *(const float4*)(x + xbase + (size_t)m * 512 + 256 + c);
        float4 o;
        o.x = mx.x * vv.x; o.y = mx.y * vv.y; o.z = mx.z * vv.z; o.w = mx.w * vv.w;
        *(float4*)(out + obase + (m << 8) + c) = o;
    }
}

extern "C" void kernel_launch(void* const* d_in, const int* in_sizes, int n_in,
                              void* d_out, int out_size, void* d_ws, size_t ws_size,
                              hipStream_t stream) {
    const float* x       = (const float*)d_in[0];
    const float* norm_w  = (const float*)d_in[1];
    const float* norm_b  = (const float*)d_in[2];
    const float* centers = (const float*)d_in[3];
    const float* spreads = (const float*)d_in[4];
    const float* tbias   = (const float*)d_in[5];
    float* out = (float*)d_out;

    const int nbw = in_sizes[0] / (64 * 512);   // b * BLOCKS = 4096
    hipLaunchKernelGGL(sgating_kernel, dim3(nbw), dim3(512), 0, stream,
                       x, norm_w, norm_b, centers, spreads, tbias, out);
}

// Round 2
// 161.782 us; speedup vs baseline: 1.7184x; 1.7184x over previous
//
#include <hip/hip_runtime.h>
#include <cstdint>

#if __has_builtin(__builtin_amdgcn_exp2f)
#define EXP2F(x) __builtin_amdgcn_exp2f(x)
#else
#define EXP2F(x) exp2f(x)
#endif

typedef _Float16 half8 __attribute__((ext_vector_type(8)));
typedef float    f32x4 __attribute__((ext_vector_type(4)));

// Layout facts:
//  x: (4,1024,64,512) f32; u = x[...,0:256], v = x[...,256:512]
//  d = vd*16 + s (s = head = d&15, vd = d>>4); head params index hb = s*1024 + w
//  score(m,n) = ax*dx + ay*dy - 0.5*(dx^2+dy^2); dx = (n&7)-(m&7), dy = (m>>3)-(n>>3)
//  mixed[m,vd,s] = softmax_n(score) . Us[n,vd,s]; out = (mixed + bias[w,m]) * v
//
// MFMA plan (per head s): D'[vd,m] = U^T (16x64) * W^T (64x64, 4 N-tiles), K = n.
//  A-frag (U^T): lane l holds row vd = l&15, k = n = 8*(l>>4)+j (+32*kt) -> reads
//    Us[s][n][vd] stride-16 b32 (4-way conflict). W^T computed in-register (exp2),
//  row sums via shfl_xor(16,32); D' col = m = 16*nt + (l&15) so inv/bias are
//  per-lane scalars. Epilogue: contiguous vd -> ds_write_b128 into
//  mixed2[m][s*16+vd] XOR-swizzled by ((m&7)<<2).

__global__ __launch_bounds__(512, 4) void sgating_kernel(
    const float* __restrict__ x,
    const float* __restrict__ norm_w,
    const float* __restrict__ norm_b,
    const float* __restrict__ centers,
    const float* __restrict__ spreads,
    const float* __restrict__ tbias,
    float* __restrict__ out)
{
    // 64KB: phase 1-2 = Us[s=16][n=64][vd=16] f32; phase 2.5-3 = mixed2[m=64][256]
    __shared__ __align__(16) float smem[16 * 64 * 16];

    const int t     = threadIdx.x;
    const int wv    = t >> 6;
    const int lane  = t & 63;
    const int bw    = blockIdx.x;       // b*1024 + w
    const int w_idx = bw & 1023;
    const size_t xbase = (size_t)bw * (64 * 512);

    // ---------------- Phase 1: LayerNorm(u) -> Us[s][n][vd] ----------------
    {
        const float4 w4 = *(const float4*)(norm_w + lane * 4);
        const float4 b4 = *(const float4*)(norm_b + lane * 4);
#pragma unroll
        for (int r = 0; r < 8; ++r) {
            const int n = wv * 8 + r;
            const float4 u = *(const float4*)(x + xbase + (size_t)n * 512 + lane * 4);
            float s  = u.x + u.y + u.z + u.w;
            float sq = u.x * u.x + u.y * u.y + u.z * u.z + u.w * u.w;
#pragma unroll
            for (int off = 1; off < 64; off <<= 1) {
                s  += __shfl_xor(s, off);
                sq += __shfl_xor(sq, off);
            }
            const float mean = s * (1.0f / 256.0f);
            const float var  = sq * (1.0f / 256.0f) - mean * mean;
            const float rstd = rsqrtf(var + 1e-5f);
            float g[4];
            g[0] = (u.x - mean) * rstd * w4.x + b4.x;
            g[1] = (u.y - mean) * rstd * w4.y + b4.y;
            g[2] = (u.z - mean) * rstd * w4.z + b4.z;
            g[3] = (u.w - mean) * rstd * w4.w + b4.w;
#pragma unroll
            for (int j = 0; j < 4; ++j) {
                const int d = lane * 4 + j;
                smem[((d & 15) << 10) + (n << 4) + (d >> 4)] = g[j];
            }
        }
    }
    __syncthreads();

    // ---------------- Phase 2: per-head MFMA softmax mixing ----------------
    const int vd16 = lane & 15;
    const int g    = lane >> 4;
    const float LOG2E = 1.4426950408889634f;
    const float C2    = 0.72134752044448f;   // 0.5*log2(e)

    float bias4[4];
#pragma unroll
    for (int nt = 0; nt < 4; ++nt)
        bias4[nt] = tbias[w_idx * 64 + nt * 16 + vd16];

    f32x4 vals[2][4];

#pragma unroll
    for (int hh = 0; hh < 2; ++hh) {
        const int s  = wv + 8 * hh;
        const int hb = (s << 10) | w_idx;
        float a = spreads[hb]; a *= a;
        const float axl = a * centers[2 * hb + 0] * LOG2E;
        const float ayl = a * centers[2 * hb + 1] * LOG2E;

        // A-frags: normalized u for head s (row = vd16, k = n)
        half8 ua[2];
#pragma unroll
        for (int kt = 0; kt < 2; ++kt) {
            const float* base = smem + (s << 10) + ((g * 8 + 32 * kt) << 4) + vd16;
#pragma unroll
            for (int j = 0; j < 8; ++j)
                ua[kt][j] = (_Float16)base[j << 4];
        }

        const float mx = (float)(vd16 & 7);
        f32x4 acc[4];
        float rs[4];
#pragma unroll
        for (int nt = 0; nt < 4; ++nt) {
            acc[nt] = (f32x4){0.f, 0.f, 0.f, 0.f};
            rs[nt] = 0.f;
        }

#pragma unroll
        for (int nt = 0; nt < 4; ++nt) {
            const float my = (float)(2 * nt + (vd16 >> 3));   // m = 16*nt + vd16
#pragma unroll
            for (int kt = 0; kt < 2; ++kt) {
                const float ny = (float)(g + 4 * kt);
                const float dy = my - ny;
                const float ty = ayl * dy - C2 * dy * dy;
                half8 wb;
#pragma unroll
                for (int j = 0; j < 8; ++j) {
                    const float dx = (float)j - mx;            // nx - mx
                    const float sc = fmaf(dx, fmaf(-C2, dx, axl), ty);
                    const float e  = EXP2F(sc);
                    rs[nt] += e;
                    wb[j] = (_Float16)e;
                }
                acc[nt] = __builtin_amdgcn_mfma_f32_16x16x32_f16(ua[kt], wb, acc[nt], 0, 0, 0);
            }
        }

        // softmax denominators (rows m = 16*nt + vd16, partial per g) + epilogue
#pragma unroll
        for (int nt = 0; nt < 4; ++nt) {
            float r = rs[nt];
            r += __shfl_xor(r, 16);
            r += __shfl_xor(r, 32);
            const float inv = 1.0f / r;
#pragma unroll
            for (int j = 0; j < 4; ++j)
                vals[hh][nt][j] = acc[nt][j] * inv + bias4[nt];
        }
    }

    __syncthreads();   // all waves done reading Us; smem becomes mixed2[64][256]

    // write mixed2[m][(s*16 + vd) ^ ((m&7)<<2)]; per lane: m = 16*nt+vd16, vd = 4g+j
#pragma unroll
    for (int hh = 0; hh < 2; ++hh) {
        const int s = wv + 8 * hh;
#pragma unroll
        for (int nt = 0; nt < 4; ++nt) {
            const int m = nt * 16 + vd16;
            const int q = (s * 16 + g * 4) ^ ((m & 7) << 2);
            *(f32x4*)(smem + (m << 8) + q) = vals[hh][nt];
        }
    }
    __syncthreads();

    // ---------------- Phase 3: out = mixed * v (coalesced) ----------------
    const size_t obase = (size_t)bw * (64 * 256);
#pragma unroll
    for (int k = 0; k < 8; ++k) {
        const int flat = (t << 2) + (k << 11);
        const int m  = flat >> 8;
        const int c  = flat & 255;        // 4 consecutive d: vd const, s = (c&15)+i
        const int vd = c >> 4;
        const int s0 = c & 15;
        const int sw = (m & 7) << 2;
        float4 mx;
        mx.x = smem[(m << 8) + ((((s0 + 0) << 4) + vd) ^ sw)];
        mx.y = smem[(m << 8) + ((((s0 + 1) << 4) + vd) ^ sw)];
        mx.z = smem[(m << 8) + ((((s0 + 2) << 4) + vd) ^ sw)];
        mx.w = smem[(m << 8) + ((((s0 + 3) << 4) + vd) ^ sw)];
        const float4 vv = *(const float4*)(x + xbase + (size_t)m * 512 + 256 + c);
        float4 o;
        o.x = mx.x * vv.x; o.y = mx.y * vv.y; o.z = mx.z * vv.z; o.w = mx.w * vv.w;
        *(float4*)(out + obase + (m << 8) + c) = o;
    }
}

extern "C" void kernel_launch(void* const* d_in, const int* in_sizes, int n_in,
                              void* d_out, int out_size, void* d_ws, size_t ws_size,
                              hipStream_t stream) {
    const float* x       = (const float*)d_in[0];
    const float* norm_w  = (const float*)d_in[1];
    const float* norm_b  = (const float*)d_in[2];
    const float* centers = (const float*)d_in[3];
    const float* spreads = (const float*)d_in[4];
    const float* tbias   = (const float*)d_in[5];
    float* out = (float*)d_out;

    const int nbw = in_sizes[0] / (64 * 512);   // 4096
    hipLaunchKernelGGL(sgating_kernel, dim3(nbw), dim3(512), 0, stream,
                       x, norm_w, norm_b, centers, spreads, tbias, out);
}

// Round 3
// 158.965 us; speedup vs baseline: 1.7489x; 1.0177x over previous
//
#include <hip/hip_runtime.h>
#include <cstdint>

#if __has_builtin(__builtin_amdgcn_exp2f)
#define EXP2F(x) __builtin_amdgcn_exp2f(x)
#else
#define EXP2F(x) exp2f(x)
#endif

typedef _Float16 half8 __attribute__((ext_vector_type(8)));
typedef float    f32x4 __attribute__((ext_vector_type(4)));

// x: (4,1024,64,512) f32; u = x[...,0:256], v = x[...,256:512]
// d = vd*16 + s (s = head = d&15, vd = d>>4); head params index hb = s*1024 + w
// score(m,n) = ax*dx + ay*dy - 0.5*(dx^2+dy^2); dx = (n&7)-(m&7), dy = (m>>3)-(n>>3)
// mixed[m,vd,s] = softmax_n(score) . Us[n,vd,s]; out = (mixed + bias[w,m]) * v
//
// LDS (32 KB, two lives):
//  life 1: Us[s=16][vd=16][nb=8][ni=8] f16, n = 8*nb+ni, block nb stored at nb^(vd&7)
//          -> phase-1 writes are b128 (full bank spread), phase-2 A-frag reads are b128.
//  life 2: mixed half-tile [32][256] f32, col ^ ((m&7)<<2); epilogue split into two
//          32-row halves so the same 32 KB serves both (vals kept in registers).
// exp separability: exp2(axl*dx - C2*dx^2) * exp2(ayl*dy - C2*dy^2) == exp2(score*log2e)
//  -> 16 exp2 per head per lane instead of 64; rs[nt] = sx * sum_kt ey (distributivity).

__global__ __launch_bounds__(512, 6) void sgating_kernel(
    const float* __restrict__ x,
    const float* __restrict__ norm_w,
    const float* __restrict__ norm_b,
    const float* __restrict__ centers,
    const float* __restrict__ spreads,
    const float* __restrict__ tbias,
    float* __restrict__ out)
{
    __shared__ __align__(16) float smem[8192];   // 32 KB
    _Float16* Us = (_Float16*)smem;

    const int t     = threadIdx.x;
    const int wv    = t >> 6;
    const int lane  = t & 63;
    const int bw    = blockIdx.x;       // b*1024 + w
    const int w_idx = bw & 1023;
    const size_t xbase = (size_t)bw * (64 * 512);

    // ---------------- Phase 1: LayerNorm(u) -> Us f16 ----------------
    {
        const float4 w4 = *(const float4*)(norm_w + lane * 4);
        const float4 b4 = *(const float4*)(norm_b + lane * 4);
        half8 uar[4];
#pragma unroll
        for (int r = 0; r < 8; ++r) {
            const int n = wv * 8 + r;
            const float4 u = *(const float4*)(x + xbase + (size_t)n * 512 + lane * 4);
            float s  = u.x + u.y + u.z + u.w;
            float sq = u.x*u.x + u.y*u.y + u.z*u.z + u.w*u.w;
#pragma unroll
            for (int off = 1; off < 64; off <<= 1) {
                s  += __shfl_xor(s, off);
                sq += __shfl_xor(sq, off);
            }
            const float mean = s * (1.0f/256.0f);
            const float var  = sq * (1.0f/256.0f) - mean*mean;
            const float rstd = rsqrtf(var + 1e-5f);
            uar[0][r] = (_Float16)((u.x - mean)*rstd*w4.x + b4.x);
            uar[1][r] = (_Float16)((u.y - mean)*rstd*w4.y + b4.y);
            uar[2][r] = (_Float16)((u.z - mean)*rstd*w4.z + b4.z);
            uar[3][r] = (_Float16)((u.w - mean)*rstd*w4.w + b4.w);
        }
#pragma unroll
        for (int j = 0; j < 4; ++j) {
            const int d  = lane * 4 + j;
            const int s  = d & 15;
            const int vd = d >> 4;
            const int nb = wv ^ (vd & 7);
            *(half8*)(Us + (s << 10) + (vd << 6) + (nb << 3)) = uar[j];
        }
    }
    __syncthreads();

    // ---------------- Phase 2: per-head MFMA softmax mixing ----------------
    const int vd16 = lane & 15;
    const int g    = lane >> 4;
    const float LOG2E = 1.4426950408889634f;
    const float C2    = 0.72134752044448f;   // 0.5*log2(e)

    float bias4[4];
#pragma unroll
    for (int nt = 0; nt < 4; ++nt)
        bias4[nt] = tbias[w_idx * 64 + nt * 16 + vd16];

    const float mx  = (float)(vd16 & 7);
    const float myb = (float)(vd16 >> 3);    // my = 2*nt + myb

    f32x4 vals[2][4];

#pragma unroll
    for (int hh = 0; hh < 2; ++hh) {
        const int s  = wv + 8 * hh;
        const int hb = (s << 10) | w_idx;
        float a = spreads[hb]; a *= a;
        const float axl = a * centers[2*hb + 0] * LOG2E;
        const float ayl = a * centers[2*hb + 1] * LOG2E;

        half8 ua[2];
#pragma unroll
        for (int kt = 0; kt < 2; ++kt) {
            const int nb = (g + 4*kt) ^ (vd16 & 7);
            ua[kt] = *(const half8*)(Us + (s << 10) + (vd16 << 6) + (nb << 3));
        }

        float ex[8];
        float sx = 0.f;
#pragma unroll
        for (int j = 0; j < 8; ++j) {
            const float dx = (float)j - mx;
            ex[j] = EXP2F(dx * fmaf(-C2, dx, axl));   // axl*dx - C2*dx^2
            sx += ex[j];
        }

        f32x4 acc[4];
        float rs[4];
#pragma unroll
        for (int nt = 0; nt < 4; ++nt) {
            acc[nt] = (f32x4){0.f,0.f,0.f,0.f};
            rs[nt] = 0.f;
        }

#pragma unroll
        for (int nt = 0; nt < 4; ++nt) {
            const float my = (float)(2*nt) + myb;
#pragma unroll
            for (int kt = 0; kt < 2; ++kt) {
                const float dy  = my - (float)(g + 4*kt);
                const float eyv = EXP2F(dy * fmaf(-C2, dy, ayl));  // ayl*dy - C2*dy^2
                rs[nt] += eyv;
                half8 wb;
#pragma unroll
                for (int j = 0; j < 8; ++j)
                    wb[j] = (_Float16)(ex[j] * eyv);
                acc[nt] = __builtin_amdgcn_mfma_f32_16x16x32_f16(ua[kt], wb, acc[nt], 0, 0, 0);
            }
        }

#pragma unroll
        for (int nt = 0; nt < 4; ++nt) {
            float r = rs[nt] * sx;     // partial row sum for this lane's two n-blocks
            r += __shfl_xor(r, 16);
            r += __shfl_xor(r, 32);
            const float inv = 1.0f / r;
#pragma unroll
            for (int j = 0; j < 4; ++j)
                vals[hh][nt][j] = acc[nt][j] * inv + bias4[nt];
        }
    }

    __syncthreads();   // Us dead; smem becomes mixed[32][256] (two passes)

    // ---------------- Phase 2.5/3: two 32-row halves ----------------
    const size_t obase = (size_t)bw * (64 * 256);
#pragma unroll
    for (int h = 0; h < 2; ++h) {
        // write mixed rows 32h..32h+31: lane m = nt*16 + vd16, cols s*16+4g..+3
#pragma unroll
        for (int hh = 0; hh < 2; ++hh) {
            const int s = wv + 8 * hh;
#pragma unroll
            for (int q = 0; q < 2; ++q) {
                const int nt  = 2*h + q;
                const int m   = nt * 16 + vd16;
                const int col = (s * 16 + g * 4) ^ ((m & 7) << 2);
                *(f32x4*)(smem + ((m & 31) << 8) + col) = vals[hh][nt];
            }
        }
        __syncthreads();

        // out rows 32h..32h+31: coalesced float4
#pragma unroll
        for (int k = 0; k < 4; ++k) {
            const int flat = (t << 2) + (k << 11);
            const int mr = flat >> 8;            // 0..31
            const int m  = mr + 32 * h;
            const int c  = flat & 255;           // d = c; vd = c>>4, s = c&15
            const int vd = c >> 4;
            const int s0 = c & 15;
            const int sw = (m & 7) << 2;
            float4 mxv;
            mxv.x = smem[(mr << 8) + ((((s0 + 0) << 4) + vd) ^ sw)];
            mxv.y = smem[(mr << 8) + ((((s0 + 1) << 4) + vd) ^ sw)];
            mxv.z = smem[(mr << 8) + ((((s0 + 2) << 4) + vd) ^ sw)];
            mxv.w = smem[(mr << 8) + ((((s0 + 3) << 4) + vd) ^ sw)];
            const float4 vv = *(const float4*)(x + xbase + (size_t)m * 512 + 256 + c);
            float4 o;
            o.x = mxv.x * vv.x; o.y = mxv.y * vv.y;
            o.z = mxv.z * vv.z; o.w = mxv.w * vv.w;
            *(float4*)(out + obase + (m << 8) + c) = o;
        }
        if (h == 0) __syncthreads();
    }
}

extern "C" void kernel_launch(void* const* d_in, const int* in_sizes, int n_in,
                              void* d_out, int out_size, void* d_ws, size_t ws_size,
                              hipStream_t stream) {
    const float* x       = (const float*)d_in[0];
    const float* norm_w  = (const float*)d_in[1];
    const float* norm_b  = (const float*)d_in[2];
    const float* centers = (const float*)d_in[3];
    const float* spreads = (const float*)d_in[4];
    const float* tbias   = (const float*)d_in[5];
    float* out = (float*)d_out;

    const int nbw = in_sizes[0] / (64 * 512);   // 4096
    hipLaunchKernelGGL(sgating_kernel, dim3(nbw), dim3(512), 0, stream,
                       x, norm_w, norm_b, centers, spreads, tbias, out);
}

// Round 4
// 157.510 us; speedup vs baseline: 1.7650x; 1.0092x over previous
//
#include <hip/hip_runtime.h>
#include <cstdint>

#if __has_builtin(__builtin_amdgcn_exp2f)
#define EXP2F(x) __builtin_amdgcn_exp2f(x)
#else
#define EXP2F(x) exp2f(x)
#endif

typedef _Float16 half8 __attribute__((ext_vector_type(8)));
typedef float    f32x4 __attribute__((ext_vector_type(4)));

// x: (4,1024,64,512) f32; u = x[...,0:256], v = x[...,256:512]
// d = vd*16 + s (s = head = d&15, vd = d>>4); head params index hb = s*1024 + w
// score(m,n) = ax*dx + ay*dy - 0.5*(dx^2+dy^2); dx = (n&7)-(m&7), dy = (m>>3)-(n>>3)
// mixed[m,vd,s] = softmax_n(score) . Us[n,vd,s]; out = (mixed + bias[w,m]) * v
//
// Structure (round 4): quarter-pipelined epilogue.
//  LDS 48 KB: Us f16 [s=16][vd=16][nb=8][ni=8] (32 KB, nb stored at nb^(vd&7)),
//             Qm f32 [16][256] quarter buffer (16 KB, col ^ ((m&7)<<2)).
//  Per nt-quarter (16 m-rows): write vals -> bar -> {compute next quarter's
//  MFMA/exp  ||  epilogue: v loads + out stores} -> bar.  3 WGs/CU (LDS 48K,
//  VGPR target <=85 via low liveness: ua reloaded per quarter, ex packed f16).

__global__ __launch_bounds__(512, 6) void sgating_kernel(
    const float* __restrict__ x,
    const float* __restrict__ norm_w,
    const float* __restrict__ norm_b,
    const float* __restrict__ centers,
    const float* __restrict__ spreads,
    const float* __restrict__ tbias,
    float* __restrict__ out)
{
    __shared__ __align__(16) float smem[12288];   // 48 KB
    _Float16* Us = (_Float16*)smem;               // first 32 KB
    float*    Qm = smem + 8192;                   // 16 KB quarter buffer

    const int t     = threadIdx.x;
    const int wv    = t >> 6;
    const int lane  = t & 63;
    const int bw    = blockIdx.x;       // b*1024 + w
    const int w_idx = bw & 1023;
    const size_t xbase = (size_t)bw * (64 * 512);
    const size_t obase = (size_t)bw * (64 * 256);

    // ---------------- Phase 1: LayerNorm(u) -> Us f16 ----------------
    {
        const float4 w4 = *(const float4*)(norm_w + lane * 4);
        const float4 b4 = *(const float4*)(norm_b + lane * 4);
        half8 uar[4];
#pragma unroll
        for (int r = 0; r < 8; ++r) {
            const int n = wv * 8 + r;
            const float4 u = *(const float4*)(x + xbase + (size_t)n * 512 + lane * 4);
            float s  = u.x + u.y + u.z + u.w;
            float sq = u.x*u.x + u.y*u.y + u.z*u.z + u.w*u.w;
#pragma unroll
            for (int off = 1; off < 64; off <<= 1) {
                s  += __shfl_xor(s, off);
                sq += __shfl_xor(sq, off);
            }
            const float mean = s * (1.0f/256.0f);
            const float var  = sq * (1.0f/256.0f) - mean*mean;
            const float rstd = rsqrtf(var + 1e-5f);
            uar[0][r] = (_Float16)((u.x - mean)*rstd*w4.x + b4.x);
            uar[1][r] = (_Float16)((u.y - mean)*rstd*w4.y + b4.y);
            uar[2][r] = (_Float16)((u.z - mean)*rstd*w4.z + b4.z);
            uar[3][r] = (_Float16)((u.w - mean)*rstd*w4.w + b4.w);
        }
#pragma unroll
        for (int j = 0; j < 4; ++j) {
            const int d  = lane * 4 + j;
            const int s  = d & 15;
            const int vd = d >> 4;
            const int nb = wv ^ (vd & 7);
            *(half8*)(Us + (s << 10) + (vd << 6) + (nb << 3)) = uar[j];
        }
    }
    __syncthreads();

    // ---------------- Phase 2 setup ----------------
    const int m16 = lane & 15;          // m-component (C/D col); also A-row index vd
    const int g   = lane >> 4;
    const float LOG2E = 1.4426950408889634f;
    const float C2    = 0.72134752044448f;   // 0.5*log2(e)
    const float mx  = (float)(m16 & 7);
    const float myb = (float)(m16 >> 3);

    const int sA = wv, sB = wv + 8;

    float bias4[4];
#pragma unroll
    for (int nt = 0; nt < 4; ++nt)
        bias4[nt] = tbias[w_idx * 64 + nt * 16 + m16];

    float aylA, aylB, sxA, sxB;
    half8 exhA, exhB;
    {
        const int hbA = (sA << 10) | w_idx;
        const int hbB = (sB << 10) | w_idx;
        float aq = spreads[hbA]; aq *= aq;
        const float axlA = aq * centers[2*hbA] * LOG2E;
        aylA = aq * centers[2*hbA + 1] * LOG2E;
        aq = spreads[hbB]; aq *= aq;
        const float axlB = aq * centers[2*hbB] * LOG2E;
        aylB = aq * centers[2*hbB + 1] * LOG2E;
        sxA = 0.f; sxB = 0.f;
#pragma unroll
        for (int j = 0; j < 8; ++j) {
            const float dx = (float)j - mx;
            const float eA = EXP2F(dx * fmaf(-C2, dx, axlA));
            const float eB = EXP2F(dx * fmaf(-C2, dx, axlB));
            sxA += eA; sxB += eB;
            exhA[j] = (_Float16)eA;
            exhB[j] = (_Float16)eB;
        }
    }

    auto compute_quarter = [&](int nt, f32x4& vOutA, f32x4& vOutB) {
        const float my = (float)(2*nt) + myb;
        f32x4 aA = (f32x4){0.f,0.f,0.f,0.f};
        f32x4 aB = (f32x4){0.f,0.f,0.f,0.f};
        float rsA = 0.f, rsB = 0.f;
#pragma unroll
        for (int kt = 0; kt < 2; ++kt) {
            const int nb = (g + 4*kt) ^ (m16 & 7);
            const half8 uA = *(const half8*)(Us + (sA << 10) + (m16 << 6) + (nb << 3));
            const half8 uB = *(const half8*)(Us + (sB << 10) + (m16 << 6) + (nb << 3));
            const float dy  = my - (float)(g + 4*kt);
            const float eA = EXP2F(dy * fmaf(-C2, dy, aylA));
            const float eB = EXP2F(dy * fmaf(-C2, dy, aylB));
            rsA += eA; rsB += eB;
            const _Float16 ehA = (_Float16)eA;
            const _Float16 ehB = (_Float16)eB;
            half8 wA, wB;
#pragma unroll
            for (int j = 0; j < 8; ++j) {
                wA[j] = exhA[j] * ehA;     // v_pk_mul_f16 pairs
                wB[j] = exhB[j] * ehB;
            }
            aA = __builtin_amdgcn_mfma_f32_16x16x32_f16(uA, wA, aA, 0, 0, 0);
            aB = __builtin_amdgcn_mfma_f32_16x16x32_f16(uB, wB, aB, 0, 0, 0);
        }
        float rA = rsA * sxA;
        rA += __shfl_xor(rA, 16); rA += __shfl_xor(rA, 32);
        float rB = rsB * sxB;
        rB += __shfl_xor(rB, 16); rB += __shfl_xor(rB, 32);
        const float iA = 1.0f / rA;
        const float iB = 1.0f / rB;
        const float bm = bias4[nt];
#pragma unroll
        for (int j = 0; j < 4; ++j) {
            vOutA[j] = aA[j] * iA + bm;
            vOutB[j] = aB[j] * iB + bm;
        }
    };

    // ---------------- Phase 2/3: quarter-pipelined ----------------
    f32x4 vA, vB, nA, nB;
    compute_quarter(0, vA, vB);

#pragma unroll
    for (int nt = 0; nt < 4; ++nt) {
        // write this quarter: rows (quarter-local) = m16, cols (s*16+4g..+3)^swz
        const int swz = (m16 & 7) << 2;
        *(f32x4*)(Qm + (m16 << 8) + ((sA * 16 + g * 4) ^ swz)) = vA;
        *(f32x4*)(Qm + (m16 << 8) + ((sB * 16 + g * 4) ^ swz)) = vB;
        __syncthreads();

        if (nt < 3) compute_quarter(nt + 1, nA, nB);   // overlaps epilogue below

        // epilogue: rows m = 16*nt + mr, mr = wv (k=0), wv+8 (k=1)
#pragma unroll
        for (int k = 0; k < 2; ++k) {
            const int mr = wv + 8 * k;
            const int m  = nt * 16 + mr;
            const int c4 = lane * 4;
            const int vd = c4 >> 4;
            const int s0 = c4 & 15;
            const int sw2 = (m & 7) << 2;
            float4 mxv;
            mxv.x = Qm[(mr << 8) + ((((s0 + 0) << 4) + vd) ^ sw2)];
            mxv.y = Qm[(mr << 8) + ((((s0 + 1) << 4) + vd) ^ sw2)];
            mxv.z = Qm[(mr << 8) + ((((s0 + 2) << 4) + vd) ^ sw2)];
            mxv.w = Qm[(mr << 8) + ((((s0 + 3) << 4) + vd) ^ sw2)];
            const float4 vv = *(const float4*)(x + xbase + (size_t)m * 512 + 256 + c4);
            float4 o;
            o.x = mxv.x * vv.x; o.y = mxv.y * vv.y;
            o.z = mxv.z * vv.z; o.w = mxv.w * vv.w;
            *(float4*)(out + obase + m * 256 + c4) = o;
        }

        if (nt < 3) {
            __syncthreads();
            vA = nA; vB = nB;
        }
    }
}

extern "C" void kernel_launch(void* const* d_in, const int* in_sizes, int n_in,
                              void* d_out, int out_size, void* d_ws, size_t ws_size,
                              hipStream_t stream) {
    const float* x       = (const float*)d_in[0];
    const float* norm_w  = (const float*)d_in[1];
    const float* norm_b  = (const float*)d_in[2];
    const float* centers = (const float*)d_in[3];
    const float* spreads = (const float*)d_in[4];
    const float* tbias   = (const float*)d_in[5];
    float* out = (float*)d_out;

    const int nbw = in_sizes[0] / (64 * 512);   // 4096
    hipLaunchKernelGGL(sgating_kernel, dim3(nbw), dim3(512), 0, stream,
                       x, norm_w, norm_b, centers, spreads, tbias, out);
}

// Round 6
// 156.255 us; speedup vs baseline: 1.7792x; 1.0080x over previous
//
#include <hip/hip_runtime.h>
#include <cstdint>

#if __has_builtin(__builtin_amdgcn_exp2f)
#define EXP2F(x) __builtin_amdgcn_exp2f(x)
#else
#define EXP2F(x) exp2f(x)
#endif

typedef _Float16 half8 __attribute__((ext_vector_type(8)));
typedef _Float16 half4 __attribute__((ext_vector_type(4)));
typedef float    f32x4 __attribute__((ext_vector_type(4)));

// x: (4,1024,64,512) f32; u = x[...,0:256], v = x[...,256:512]
// d = vd*16 + s (head s = d&15); head params hb = s*1024 + w
// score(m,n) = ax*dx + ay*dy - 0.5*(dx^2+dy^2); dx = (n&7)-(m&7), dy = (m>>3)-(n>>3)
// mixed[m,vd,s] = softmax_n(score).Us[n,vd,s]; out = (mixed + bias[w,m]) * v
//
// Round 5: SINGLE-PASS x read. Phase 1 reads full 2KB rows (u+v); v kept in
// 16 VGPRs (f16). Row permutation n = r*8+wv so wave wv's v-rows = {16nt+wv,
// 16nt+8+wv} — exactly its epilogue rows each quarter. Us layout transposed:
// [s][vd][qb][j], n = 8j+q, qb = q^(vd&7) (same addresses/swizzle as round 4;
// nx=q, ny=j roles swapped in weight math; ey = 14-entry f16 table shared
// across nt since dy(nt+1,j+2)=dy(nt,j)). Epilogue: LDS + NT stores only.

__global__ __launch_bounds__(512, 4) void sgating_kernel(
    const float* __restrict__ x,
    const float* __restrict__ norm_w,
    const float* __restrict__ norm_b,
    const float* __restrict__ centers,
    const float* __restrict__ spreads,
    const float* __restrict__ tbias,
    float* __restrict__ out)
{
    __shared__ __align__(16) float smem[12288];   // 48 KB: Us 32K + Qm 16K
    _Float16* Us = (_Float16*)smem;
    float*    Qm = smem + 8192;

    const int t     = threadIdx.x;
    const int wv    = t >> 6;
    const int lane  = t & 63;
    const int bw    = blockIdx.x;       // b*1024 + w
    const int w_idx = bw & 1023;
    const size_t xbase = (size_t)bw * (64 * 512);
    const size_t obase = (size_t)bw * (64 * 256);

    half4 vreg[8];                      // v rows r*8+wv, elems lane*4..+3 (f16)

    // ---------------- Phase 1: single-pass load + LayerNorm(u) -> Us ----------------
    {
        const float4 w4 = *(const float4*)(norm_w + lane * 4);
        const float4 b4 = *(const float4*)(norm_b + lane * 4);
        half8 uar[4];
#pragma unroll
        for (int r = 0; r < 8; ++r) {
            const int n = r * 8 + wv;
            const float* rowp = x + xbase + (size_t)n * 512 + lane * 4;
            const float4 u  = *(const float4*)(rowp);
            const float4 vv = *(const float4*)(rowp + 256);
            vreg[r][0] = (_Float16)vv.x; vreg[r][1] = (_Float16)vv.y;
            vreg[r][2] = (_Float16)vv.z; vreg[r][3] = (_Float16)vv.w;
            float s  = u.x + u.y + u.z + u.w;
            float sq = u.x*u.x + u.y*u.y + u.z*u.z + u.w*u.w;
#pragma unroll
            for (int off = 1; off < 64; off <<= 1) {
                s  += __shfl_xor(s, off);
                sq += __shfl_xor(sq, off);
            }
            const float mean = s * (1.0f/256.0f);
            const float var  = sq * (1.0f/256.0f) - mean*mean;
            const float rstd = rsqrtf(var + 1e-5f);
            uar[0][r] = (_Float16)((u.x - mean)*rstd*w4.x + b4.x);
            uar[1][r] = (_Float16)((u.y - mean)*rstd*w4.y + b4.y);
            uar[2][r] = (_Float16)((u.z - mean)*rstd*w4.z + b4.z);
            uar[3][r] = (_Float16)((u.w - mean)*rstd*w4.w + b4.w);
        }
        // uar[j][r] = value at n = r*8+wv (q = wv, j-slot = r) -> contiguous b128
#pragma unroll
        for (int j = 0; j < 4; ++j) {
            const int d  = lane * 4 + j;
            const int s  = d & 15;
            const int vd = d >> 4;
            const int qb = wv ^ (vd & 7);
            *(half8*)(Us + (s << 10) + (vd << 6) + (qb << 3)) = uar[j];
        }
    }
    __syncthreads();

    // ---------------- Phase 2 setup ----------------
    const int m16 = lane & 15;
    const int g   = lane >> 4;
    const float LOG2E = 1.4426950408889634f;
    const float C2    = 0.72134752044448f;   // 0.5*log2(e)
    const float mx  = (float)(m16 & 7);
    const float myb = (float)(m16 >> 3);
    const int sA = wv, sB = wv + 8;

    float bias4[4];
#pragma unroll
    for (int nt = 0; nt < 4; ++nt)
        bias4[nt] = tbias[w_idx * 64 + nt * 16 + m16];

    float    exfA[2], exfB[2];
    _Float16 exhA[2], exhB[2];
    half8 EYA_[2], EYB_[2];     // 14-entry f16 ey tables, i -> dy = i-7+myb
    {
        const int hbA = (sA << 10) | w_idx;
        const int hbB = (sB << 10) | w_idx;
        float aq = spreads[hbA]; aq *= aq;
        const float axlA = aq * centers[2*hbA]     * LOG2E;
        const float aylA = aq * centers[2*hbA + 1] * LOG2E;
        aq = spreads[hbB]; aq *= aq;
        const float axlB = aq * centers[2*hbB]     * LOG2E;
        const float aylB = aq * centers[2*hbB + 1] * LOG2E;
#pragma unroll
        for (int kt = 0; kt < 2; ++kt) {
            const float dx = (float)(g + 4*kt) - mx;
            const float eA = EXP2F(dx * fmaf(-C2, dx, axlA));
            const float eB = EXP2F(dx * fmaf(-C2, dx, axlB));
            exfA[kt] = eA; exhA[kt] = (_Float16)eA;
            exfB[kt] = eB; exhB[kt] = (_Float16)eB;
        }
#pragma unroll
        for (int i = 0; i < 16; ++i) {
            const float dy = (float)(i - 7) + myb;
            const _Float16 eA = (i < 14) ? (_Float16)EXP2F(dy * fmaf(-C2, dy, aylA)) : (_Float16)0.f;
            const _Float16 eB = (i < 14) ? (_Float16)EXP2F(dy * fmaf(-C2, dy, aylB)) : (_Float16)0.f;
            if (i < 8) { EYA_[0][i] = eA; EYB_[0][i] = eB; }
            else       { EYA_[1][i-8] = eA; EYB_[1][i-8] = eB; }
        }
    }

#define EYAT(I) ((I) < 8 ? EYA_[0][(I)] : EYA_[1][(I)-8])
#define EYBT(I) ((I) < 8 ? EYB_[0][(I)] : EYB_[1][(I)-8])

#define CQ(NT, vOutA, vOutB) do {                                              \
    f32x4 aA = (f32x4){0.f,0.f,0.f,0.f};                                       \
    f32x4 aB = (f32x4){0.f,0.f,0.f,0.f};                                       \
    half8 eyA8, eyB8;                                                          \
    float syA = 0.f, syB = 0.f;                                                \
    _Pragma("unroll") for (int j = 0; j < 8; ++j) {                            \
        const _Float16 ea = EYAT(2*(NT)+7-j);                                  \
        const _Float16 eb = EYBT(2*(NT)+7-j);                                  \
        eyA8[j] = ea; eyB8[j] = eb;                                            \
        syA += (float)ea; syB += (float)eb;                                    \
    }                                                                          \
    _Pragma("unroll") for (int kt = 0; kt < 2; ++kt) {                         \
        const int qb = (g + 4*kt) ^ (m16 & 7);                                 \
        const half8 uA = *(const half8*)(Us + (sA<<10) + (m16<<6) + (qb<<3));  \
        const half8 uB = *(const half8*)(Us + (sB<<10) + (m16<<6) + (qb<<3));  \
        half8 wA, wB;                                                          \
        _Pragma("unroll") for (int j = 0; j < 8; ++j) {                        \
            wA[j] = eyA8[j] * exhA[kt];                                        \
            wB[j] = eyB8[j] * exhB[kt];                                        \
        }                                                                      \
        aA = __builtin_amdgcn_mfma_f32_16x16x32_f16(uA, wA, aA, 0, 0, 0);      \
        aB = __builtin_amdgcn_mfma_f32_16x16x32_f16(uB, wB, aB, 0, 0, 0);      \
    }                                                                          \
    float rA = (exfA[0] + exfA[1]) * syA;                                      \
    rA += __shfl_xor(rA, 16); rA += __shfl_xor(rA, 32);                        \
    float rB = (exfB[0] + exfB[1]) * syB;                                      \
    rB += __shfl_xor(rB, 16); rB += __shfl_xor(rB, 32);                        \
    const float iA = 1.0f / rA;                                                \
    const float iB = 1.0f / rB;                                                \
    const float bm = bias4[(NT)];                                              \
    _Pragma("unroll") for (int j = 0; j < 4; ++j) {                            \
        vOutA[j] = aA[j]*iA + bm;                                              \
        vOutB[j] = aB[j]*iB + bm;                                              \
    }                                                                          \
} while (0)

#define WRITEQ(vA_, vB_) do {                                                  \
    const int swz = (m16 & 7) << 2;                                            \
    *(f32x4*)(Qm + (m16<<8) + ((sA*16 + g*4) ^ swz)) = vA_;                    \
    *(f32x4*)(Qm + (m16<<8) + ((sB*16 + g*4) ^ swz)) = vB_;                    \
} while (0)

#define EPIK(NT, K) do {                                                       \
    const int mr  = wv + 8*(K);                                                \
    const int m   = (NT)*16 + mr;                                              \
    const int c4  = lane * 4;                                                  \
    const int vd  = c4 >> 4;                                                   \
    const int s0  = c4 & 15;                                                   \
    const int sw2 = (m & 7) << 2;                                              \
    f32x4 mxv;                                                                 \
    mxv[0] = Qm[(mr<<8) + ((((s0+0)<<4)+vd) ^ sw2)];                           \
    mxv[1] = Qm[(mr<<8) + ((((s0+1)<<4)+vd) ^ sw2)];                           \
    mxv[2] = Qm[(mr<<8) + ((((s0+2)<<4)+vd) ^ sw2)];                           \
    mxv[3] = Qm[(mr<<8) + ((((s0+3)<<4)+vd) ^ sw2)];                           \
    const half4 vh = vreg[2*(NT)+(K)];                                         \
    f32x4 o;                                                                   \
    o[0] = mxv[0] * (float)vh[0]; o[1] = mxv[1] * (float)vh[1];                \
    o[2] = mxv[2] * (float)vh[2]; o[3] = mxv[3] * (float)vh[3];                \
    __builtin_nontemporal_store(o, (f32x4*)(out + obase + m*256 + c4));        \
} while (0)

    // ---------------- Phase 2/3: quarter-pipelined (no global loads) ----------------
    f32x4 cA, cB, nA2, nB2;
    CQ(0, cA, cB);

    WRITEQ(cA, cB);
    __syncthreads();
    CQ(1, nA2, nB2);
    EPIK(0, 0); EPIK(0, 1);
    __syncthreads();
    cA = nA2; cB = nB2;

    WRITEQ(cA, cB);
    __syncthreads();
    CQ(2, nA2, nB2);
    EPIK(1, 0); EPIK(1, 1);
    __syncthreads();
    cA = nA2; cB = nB2;

    WRITEQ(cA, cB);
    __syncthreads();
    CQ(3, nA2, nB2);
    EPIK(2, 0); EPIK(2, 1);
    __syncthreads();
    cA = nA2; cB = nB2;

    WRITEQ(cA, cB);
    __syncthreads();
    EPIK(3, 0); EPIK(3, 1);
}

extern "C" void kernel_launch(void* const* d_in, const int* in_sizes, int n_in,
                              void* d_out, int out_size, void* d_ws, size_t ws_size,
                              hipStream_t stream) {
    const float* x       = (const float*)d_in[0];
    const float* norm_w  = (const float*)d_in[1];
    const float* norm_b  = (const float*)d_in[2];
    const float* centers = (const float*)d_in[3];
    const float* spreads = (const float*)d_in[4];
    const float* tbias   = (const float*)d_in[5];
    float* out = (float*)d_out;

    const int nbw = in_sizes[0] / (64 * 512);   // 4096
    hipLaunchKernelGGL(sgating_kernel, dim3(nbw), dim3(512), 0, stream,
                       x, norm_w, norm_b, centers, spreads, tbias, out);
}